// Round 1
// baseline (7017.545 us; speedup 1.0000x reference)
//
#include <hip/hip_runtime.h>
#include <hip/hip_bf16.h>

// ---------------------------------------------------------------------------
// GCN 3-layer forward:  (GCNConv -> BN) x2 -> GCNConv
// N=100000, E=1600000, IN=H=128, OUT=64
// Baseline: f32 LDS-tiled GEMM + atomic edge-scatter aggregation.
// ---------------------------------------------------------------------------

#define NNODES_K 128   // feature dims are 128 except final output 64

// ---------------- degree / dis ----------------
__global__ void deg_count_k(const int* __restrict__ dst, float* __restrict__ deg, int E) {
    int i = blockIdx.x * blockDim.x + threadIdx.x;
    if (i < E) atomicAdd(&deg[dst[i]], 1.0f);
}

__global__ void deg_to_dis_k(float* __restrict__ deg, int n) {
    int i = blockIdx.x * blockDim.x + threadIdx.x;
    if (i < n) deg[i] = rsqrtf(deg[i] + 1.0f);   // +1 self loop
}

// ---------------- GEMM: H = X @ W   (K = 128, OUTD = 128 or 64) ------------
template <int OUTD>
__global__ __launch_bounds__(256) void gemm_k(const float* __restrict__ X,
                                              const float* __restrict__ W,
                                              float* __restrict__ H, int n) {
    constexpr int K = 128;
    constexpr int ROWS = 32;
    constexpr int CQ = OUTD / 4;      // col quads per row: 32 or 16
    constexpr int TR = 256 / CQ;      // thread groups along rows: 8 or 16
    constexpr int RPT = ROWS / TR;    // rows per thread: 4 or 2

    __shared__ float ws[K * OUTD];
    __shared__ float xs[ROWS][K];

    const int tx = threadIdx.x;

    // stage W (K*OUTD floats)
    {
        const float4* W4 = (const float4*)W;
        float4* ws4 = (float4*)ws;
        constexpr int tot = K * OUTD / 4;
        for (int i = tx; i < tot; i += 256) ws4[i] = W4[i];
    }
    // stage X tile (ROWS x K)
    const int row0 = blockIdx.x * ROWS;
    {
        const float4* X4 = (const float4*)X;
        constexpr int tot = ROWS * K / 4;  // 1024
        for (int i = tx; i < tot; i += 256) {
            int r = i / (K / 4);
            int kk = i - r * (K / 4);
            int gr = row0 + r;
            float4 v = make_float4(0.f, 0.f, 0.f, 0.f);
            if (gr < n) v = X4[(size_t)gr * (K / 4) + kk];
            ((float4*)&xs[r][0])[kk] = v;
        }
    }
    __syncthreads();

    const int cq = tx % CQ;
    const int tr = tx / CQ;

    float acc[RPT][4];
#pragma unroll
    for (int r = 0; r < RPT; ++r)
#pragma unroll
        for (int c = 0; c < 4; ++c) acc[r][c] = 0.f;

#pragma unroll 8
    for (int k = 0; k < K; ++k) {
        float4 wv = ((const float4*)(&ws[k * OUTD]))[cq];
#pragma unroll
        for (int r = 0; r < RPT; ++r) {
            float xv = xs[tr * RPT + r][k];
            acc[r][0] += xv * wv.x;
            acc[r][1] += xv * wv.y;
            acc[r][2] += xv * wv.z;
            acc[r][3] += xv * wv.w;
        }
    }

#pragma unroll
    for (int r = 0; r < RPT; ++r) {
        int gr = row0 + tr * RPT + r;
        if (gr < n) {
            ((float4*)&H[(size_t)gr * OUTD])[cq] =
                make_float4(acc[r][0], acc[r][1], acc[r][2], acc[r][3]);
        }
    }
}

// --------- O[i] = H[i] * dis[i]^2 + b   (self-loop message + bias) ---------
template <int OUTD>
__global__ void agg_init_k(const float* __restrict__ H, const float* __restrict__ dis,
                           const float* __restrict__ b, float* __restrict__ O, int n) {
    constexpr int Q = OUTD / 4;
    int idx = blockIdx.x * blockDim.x + threadIdx.x;
    int tot = n * Q;
    if (idx >= tot) return;
    int i = idx / Q;
    int q = idx - i * Q;
    float d = dis[i];
    float d2 = d * d;
    float4 h = ((const float4*)H)[idx];
    float4 bb = ((const float4*)b)[q];
    float4 o;
    o.x = h.x * d2 + bb.x;
    o.y = h.y * d2 + bb.y;
    o.z = h.z * d2 + bb.z;
    o.w = h.w * d2 + bb.w;
    ((float4*)O)[idx] = o;
}

// --------- edge scatter: O[dst] += H[src] * dis[src]*dis[dst] --------------
template <int OUTD>
__global__ void agg_edges_k(const float* __restrict__ H, float* __restrict__ O,
                            const int* __restrict__ src, const int* __restrict__ dst,
                            const float* __restrict__ dis, int E) {
    constexpr int Q = OUTD / 4;
    int idx = blockIdx.x * blockDim.x + threadIdx.x;
    int tot = E * Q;           // <= 51.2M, fits int
    if (idx >= tot) return;
    int e = idx / Q;
    int q = idx - e * Q;
    int s = src[e];
    int d = dst[e];
    float coef = dis[s] * dis[d];
    float4 h = ((const float4*)H)[(size_t)s * Q + q];
    float* op = O + (size_t)d * OUTD + q * 4;
    atomicAdd(op + 0, h.x * coef);
    atomicAdd(op + 1, h.y * coef);
    atomicAdd(op + 2, h.z * coef);
    atomicAdd(op + 3, h.w * coef);
}

// ---------------- batch norm ----------------
__global__ __launch_bounds__(256) void bn_stats_k(const float* __restrict__ X,
                                                  float* __restrict__ sums,
                                                  float* __restrict__ sumsq, int n) {
    int col = threadIdx.x & 127;
    int half = threadIdx.x >> 7;
    float s = 0.f, sq = 0.f;
    for (int r = blockIdx.x * 2 + half; r < n; r += gridDim.x * 2) {
        float v = X[(size_t)r * 128 + col];
        s += v;
        sq += v * v;
    }
    __shared__ float ls[256], lq[256];
    ls[threadIdx.x] = s;
    lq[threadIdx.x] = sq;
    __syncthreads();
    if (half == 0) {
        s = ls[col] + ls[col + 128];
        sq = lq[col] + lq[col + 128];
        atomicAdd(&sums[col], s);
        atomicAdd(&sumsq[col], sq);
    }
}

__global__ void bn_finalize_k(const float* __restrict__ sums, const float* __restrict__ sumsq,
                              const float* __restrict__ g, const float* __restrict__ be,
                              float* __restrict__ scale, float* __restrict__ shift, int n) {
    int c = threadIdx.x;  // 128 threads
    float inv_n = 1.0f / (float)n;
    float m = sums[c] * inv_n;
    float v = sumsq[c] * inv_n - m * m;
    float sc = rsqrtf(v + 1e-5f) * g[c];
    scale[c] = sc;
    shift[c] = be[c] - m * sc;
}

__global__ void bn_apply_k(float* __restrict__ X, const float* __restrict__ scale,
                           const float* __restrict__ shift, int n) {
    int idx = blockIdx.x * blockDim.x + threadIdx.x;  // per float4
    int tot = n * 32;
    if (idx >= tot) return;
    int q = idx & 31;
    float4 v = ((float4*)X)[idx];
    float4 sc = ((const float4*)scale)[q];
    float4 sh = ((const float4*)shift)[q];
    v.x = v.x * sc.x + sh.x;
    v.y = v.y * sc.y + sh.y;
    v.z = v.z * sc.z + sh.z;
    v.w = v.w * sc.w + sh.w;
    ((float4*)X)[idx] = v;
}

// ---------------------------------------------------------------------------
extern "C" void kernel_launch(void* const* d_in, const int* in_sizes, int n_in,
                              void* d_out, int out_size, void* d_ws, size_t ws_size,
                              hipStream_t stream) {
    const float* x   = (const float*)d_in[0];
    const int*   ei  = (const int*)d_in[1];
    const float* W1  = (const float*)d_in[2];
    const float* b1  = (const float*)d_in[3];
    const float* g1  = (const float*)d_in[4];
    const float* be1 = (const float*)d_in[5];
    const float* W2  = (const float*)d_in[6];
    const float* b2  = (const float*)d_in[7];
    const float* g2  = (const float*)d_in[8];
    const float* be2 = (const float*)d_in[9];
    const float* W3  = (const float*)d_in[10];
    const float* b3  = (const float*)d_in[11];
    float* out = (float*)d_out;

    const int N = in_sizes[0] / 128;
    const int E = in_sizes[1] / 2;
    const int* src = ei;
    const int* dst = ei + E;

    float* ws    = (float*)d_ws;
    float* dis   = ws;                 // N floats
    float* stats = ws + N;             // 512 floats: sums|sumsq|scale|shift
    float* bufA  = stats + 512;        // N*128
    float* bufB  = bufA + (size_t)N * 128;

    float* sums  = stats;
    float* sumsq = stats + 128;
    float* scale = stats + 256;
    float* shift = stats + 384;

    const int BS = 256;
    dim3 blk(BS);

    // degree -> dis (shared by all layers)
    hipMemsetAsync(dis, 0, (size_t)N * 4, stream);
    deg_count_k<<<dim3((E + BS - 1) / BS), blk, 0, stream>>>(dst, dis, E);
    deg_to_dis_k<<<dim3((N + BS - 1) / BS), blk, 0, stream>>>(dis, N);

    const int gemm_grid = (N + 31) / 32;
    const int ew128 = (N * 32 + BS - 1) / BS;   // elementwise grid, 128 cols
    const int ag128 = (E * 32 + BS - 1) / BS;   // edge grid, 128 cols

    // ---- layer 1 ----
    gemm_k<128><<<dim3(gemm_grid), blk, 0, stream>>>(x, W1, bufA, N);
    agg_init_k<128><<<dim3(ew128), blk, 0, stream>>>(bufA, dis, b1, bufB, N);
    agg_edges_k<128><<<dim3(ag128), blk, 0, stream>>>(bufA, bufB, src, dst, dis, E);
    hipMemsetAsync(stats, 0, 256 * 4, stream);
    bn_stats_k<<<dim3(512), blk, 0, stream>>>(bufB, sums, sumsq, N);
    bn_finalize_k<<<dim3(1), dim3(128), 0, stream>>>(sums, sumsq, g1, be1, scale, shift, N);
    bn_apply_k<<<dim3(ew128), blk, 0, stream>>>(bufB, scale, shift, N);

    // ---- layer 2 ----
    gemm_k<128><<<dim3(gemm_grid), blk, 0, stream>>>(bufB, W2, bufA, N);
    agg_init_k<128><<<dim3(ew128), blk, 0, stream>>>(bufA, dis, b2, bufB, N);
    agg_edges_k<128><<<dim3(ag128), blk, 0, stream>>>(bufA, bufB, src, dst, dis, E);
    hipMemsetAsync(stats, 0, 256 * 4, stream);
    bn_stats_k<<<dim3(512), blk, 0, stream>>>(bufB, sums, sumsq, N);
    bn_finalize_k<<<dim3(1), dim3(128), 0, stream>>>(sums, sumsq, g2, be2, scale, shift, N);
    bn_apply_k<<<dim3(ew128), blk, 0, stream>>>(bufB, scale, shift, N);

    // ---- layer 3 (OUT = 64, straight to d_out) ----
    const int ew64 = (N * 16 + BS - 1) / BS;
    const int ag64 = (E * 16 + BS - 1) / BS;
    gemm_k<64><<<dim3(gemm_grid), blk, 0, stream>>>(bufB, W3, bufA, N);
    agg_init_k<64><<<dim3(ew64), blk, 0, stream>>>(bufA, dis, b3, out, N);
    agg_edges_k<64><<<dim3(ag64), blk, 0, stream>>>(bufA, out, src, dst, dis, E);
}

// Round 2
// 1227.330 us; speedup vs baseline: 5.7177x; 5.7177x over previous
//
#include <hip/hip_runtime.h>
#include <hip/hip_bf16.h>

// ---------------------------------------------------------------------------
// GCN 3-layer forward:  (GCNConv -> BN) x2 -> GCNConv
// N=100000, E=1600000, IN=H=128, OUT=64
// Round 1: CSR gather aggregation (replaces float atomic scatter),
//          BN stats fused into gather, BN apply fused into next GEMM.
// ---------------------------------------------------------------------------

// ---------------- degree ----------------
__global__ void deg_count_k(const int* __restrict__ dst, int* __restrict__ deg, int E) {
    int i = blockIdx.x * blockDim.x + threadIdx.x;
    if (i < E) atomicAdd(&deg[dst[i]], 1);
}

__global__ void deg_to_dis_k(const int* __restrict__ deg, float* __restrict__ dis, int n) {
    int i = blockIdx.x * blockDim.x + threadIdx.x;
    if (i < n) dis[i] = rsqrtf((float)deg[i] + 1.0f);   // +1 self loop
}

// ---------------- CSR build: hierarchical exclusive scan of deg ------------
__global__ __launch_bounds__(256) void scan_block_reduce_k(const int* __restrict__ deg,
                                                           int* __restrict__ blockSums, int n) {
    __shared__ int tmp[256];
    int i = blockIdx.x * 256 + threadIdx.x;
    tmp[threadIdx.x] = (i < n) ? deg[i] : 0;
    __syncthreads();
    for (int off = 128; off > 0; off >>= 1) {
        if (threadIdx.x < off) tmp[threadIdx.x] += tmp[threadIdx.x + off];
        __syncthreads();
    }
    if (threadIdx.x == 0) blockSums[blockIdx.x] = tmp[0];
}

__global__ __launch_bounds__(512) void scan_top_k(int* __restrict__ blockSums,
                                                  int* __restrict__ blockOff,
                                                  int* __restrict__ row_ptr,
                                                  int nb, int n, int E) {
    __shared__ int tmp[512];
    int tid = threadIdx.x;
    int v = (tid < nb) ? blockSums[tid] : 0;
    tmp[tid] = v;
    __syncthreads();
    for (int off = 1; off < 512; off <<= 1) {
        int t = 0;
        if (tid >= off) t = tmp[tid - off];
        __syncthreads();
        tmp[tid] += t;
        __syncthreads();
    }
    if (tid < nb) blockOff[tid] = tmp[tid] - v;   // exclusive
    if (tid == 0) row_ptr[n] = E;
}

__global__ __launch_bounds__(256) void scan_final_k(const int* __restrict__ deg,
                                                    const int* __restrict__ blockOff,
                                                    int* __restrict__ row_ptr, int n) {
    __shared__ int tmp[256];
    int tid = threadIdx.x;
    int i = blockIdx.x * 256 + tid;
    int v = (i < n) ? deg[i] : 0;
    tmp[tid] = v;
    __syncthreads();
    for (int off = 1; off < 256; off <<= 1) {
        int t = 0;
        if (tid >= off) t = tmp[tid - off];
        __syncthreads();
        tmp[tid] += t;
        __syncthreads();
    }
    if (i < n) row_ptr[i] = blockOff[blockIdx.x] + tmp[tid] - v;   // exclusive
}

__global__ void edge_scatter_k(const int* __restrict__ src, const int* __restrict__ dst,
                               const int* __restrict__ row_ptr, int* __restrict__ cursor,
                               int* __restrict__ esrc, int E) {
    int e = blockIdx.x * blockDim.x + threadIdx.x;
    if (e >= E) return;
    int d = dst[e];
    int pos = row_ptr[d] + atomicAdd(&cursor[d], 1);
    esrc[pos] = src[e];
}

// ---------------- GEMM: H = BN(X) @ W   (K = 128, OUTD = 128 or 64) --------
template <int OUTD, bool BNIN>
__global__ __launch_bounds__(256) void gemm_k(const float* __restrict__ X,
                                              const float* __restrict__ W,
                                              const float* __restrict__ scale,
                                              const float* __restrict__ shift,
                                              float* __restrict__ H, int n) {
    constexpr int K = 128;
    constexpr int ROWS = 32;
    constexpr int CQ = OUTD / 4;      // col quads per row: 32 or 16
    constexpr int TR = 256 / CQ;      // thread groups along rows: 8 or 16
    constexpr int RPT = ROWS / TR;    // rows per thread: 4 or 2

    __shared__ float ws[K * OUTD];
    __shared__ float xs[ROWS][K];

    const int tx = threadIdx.x;

    // stage W
    {
        const float4* W4 = (const float4*)W;
        float4* ws4 = (float4*)ws;
        constexpr int tot = K * OUTD / 4;
        for (int i = tx; i < tot; i += 256) ws4[i] = W4[i];
    }
    // stage X tile (ROWS x K), BN applied on the fly
    const int row0 = blockIdx.x * ROWS;
    {
        const float4* X4 = (const float4*)X;
        constexpr int tot = ROWS * K / 4;  // 1024
        for (int i = tx; i < tot; i += 256) {
            int r = i / (K / 4);
            int kk = i - r * (K / 4);
            int gr = row0 + r;
            float4 v = make_float4(0.f, 0.f, 0.f, 0.f);
            if (gr < n) {
                v = X4[(size_t)gr * (K / 4) + kk];
                if (BNIN) {
                    float4 sc = ((const float4*)scale)[kk];
                    float4 sh = ((const float4*)shift)[kk];
                    v.x = v.x * sc.x + sh.x;
                    v.y = v.y * sc.y + sh.y;
                    v.z = v.z * sc.z + sh.z;
                    v.w = v.w * sc.w + sh.w;
                }
            }
            ((float4*)&xs[r][0])[kk] = v;
        }
    }
    __syncthreads();

    const int cq = tx % CQ;
    const int tr = tx / CQ;

    float acc[RPT][4];
#pragma unroll
    for (int r = 0; r < RPT; ++r)
#pragma unroll
        for (int c = 0; c < 4; ++c) acc[r][c] = 0.f;

#pragma unroll 8
    for (int k = 0; k < K; ++k) {
        float4 wv = ((const float4*)(&ws[k * OUTD]))[cq];
#pragma unroll
        for (int r = 0; r < RPT; ++r) {
            float xv = xs[tr * RPT + r][k];
            acc[r][0] += xv * wv.x;
            acc[r][1] += xv * wv.y;
            acc[r][2] += xv * wv.z;
            acc[r][3] += xv * wv.w;
        }
    }

#pragma unroll
    for (int r = 0; r < RPT; ++r) {
        int gr = row0 + tr * RPT + r;
        if (gr < n) {
            ((float4*)&H[(size_t)gr * OUTD])[cq] =
                make_float4(acc[r][0], acc[r][1], acc[r][2], acc[r][3]);
        }
    }
}

// ---------------- gather aggregation (+ optional fused BN stats) -----------
// O[i] = b + H[i]*dis[i]^2 + sum_{e: dst=i} H[src_e] * dis[src_e]*dis[i]
template <int OUTD, bool STATS>
__global__ __launch_bounds__(256) void gather_k(const float* __restrict__ H,
                                                const float* __restrict__ dis,
                                                const float* __restrict__ b,
                                                const int* __restrict__ row_ptr,
                                                const int* __restrict__ esrc,
                                                float* __restrict__ O,
                                                float* __restrict__ sums,
                                                float* __restrict__ sumsq, int n) {
    constexpr int Q = OUTD / 4;          // float4 per row: 32 or 16
    constexpr int GROUPS = 256 / Q;      // nodes per block: 8 or 16

    __shared__ float s_sum[OUTD];
    __shared__ float s_sq[OUTD];
    if (STATS) {
        if (threadIdx.x < OUTD) { s_sum[threadIdx.x] = 0.f; s_sq[threadIdx.x] = 0.f; }
        __syncthreads();
    }

    const int g = threadIdx.x / Q;
    const int lane = threadIdx.x % Q;
    const int node = blockIdx.x * GROUPS + g;
    const bool active = node < n;

    float4 acc = make_float4(0.f, 0.f, 0.f, 0.f);
    if (active) {
        const float4* H4 = (const float4*)H;
        float di = dis[node];
        float4 h = H4[(size_t)node * Q + lane];
        float4 bb = ((const float4*)b)[lane];
        float d2 = di * di;
        acc.x = h.x * d2 + bb.x;
        acc.y = h.y * d2 + bb.y;
        acc.z = h.z * d2 + bb.z;
        acc.w = h.w * d2 + bb.w;

        int beg = row_ptr[node];
        int end = row_ptr[node + 1];
        for (int j = beg; j < end; ++j) {
            int s = esrc[j];
            float cf = dis[s] * di;
            float4 hv = H4[(size_t)s * Q + lane];
            acc.x += hv.x * cf;
            acc.y += hv.y * cf;
            acc.z += hv.z * cf;
            acc.w += hv.w * cf;
        }
        ((float4*)O)[(size_t)node * Q + lane] = acc;
    }

    if (STATS) {
        if (active) {
            atomicAdd(&s_sum[lane * 4 + 0], acc.x);
            atomicAdd(&s_sum[lane * 4 + 1], acc.y);
            atomicAdd(&s_sum[lane * 4 + 2], acc.z);
            atomicAdd(&s_sum[lane * 4 + 3], acc.w);
            atomicAdd(&s_sq[lane * 4 + 0], acc.x * acc.x);
            atomicAdd(&s_sq[lane * 4 + 1], acc.y * acc.y);
            atomicAdd(&s_sq[lane * 4 + 2], acc.z * acc.z);
            atomicAdd(&s_sq[lane * 4 + 3], acc.w * acc.w);
        }
        __syncthreads();
        if (threadIdx.x < OUTD) {
            atomicAdd(&sums[threadIdx.x], s_sum[threadIdx.x]);
            atomicAdd(&sumsq[threadIdx.x], s_sq[threadIdx.x]);
        }
    }
}

// ---------------- BN finalize: scale/shift from sums ----------------------
__global__ void bn_finalize_k(const float* __restrict__ sums, const float* __restrict__ sumsq,
                              const float* __restrict__ g, const float* __restrict__ be,
                              float* __restrict__ scale, float* __restrict__ shift, int n) {
    int c = threadIdx.x;  // 128 threads
    float inv_n = 1.0f / (float)n;
    float m = sums[c] * inv_n;
    float v = sumsq[c] * inv_n - m * m;
    float sc = rsqrtf(v + 1e-5f) * g[c];
    scale[c] = sc;
    shift[c] = be[c] - m * sc;
}

// ---------------------------------------------------------------------------
extern "C" void kernel_launch(void* const* d_in, const int* in_sizes, int n_in,
                              void* d_out, int out_size, void* d_ws, size_t ws_size,
                              hipStream_t stream) {
    const float* x   = (const float*)d_in[0];
    const int*   ei  = (const int*)d_in[1];
    const float* W1  = (const float*)d_in[2];
    const float* b1  = (const float*)d_in[3];
    const float* g1  = (const float*)d_in[4];
    const float* be1 = (const float*)d_in[5];
    const float* W2  = (const float*)d_in[6];
    const float* b2  = (const float*)d_in[7];
    const float* g2  = (const float*)d_in[8];
    const float* be2 = (const float*)d_in[9];
    const float* W3  = (const float*)d_in[10];
    const float* b3  = (const float*)d_in[11];
    float* out = (float*)d_out;

    const int N = in_sizes[0] / 128;
    const int E = in_sizes[1] / 2;
    const int* src = ei;
    const int* dst = ei + E;

    // ---- workspace layout (persistent) ----
    float* wsp   = (float*)d_ws;
    float* dis   = wsp;                               // N floats
    float* stats = wsp + N;                           // 512 floats
    float* bufA  = stats + 512;                       // N*128 (GEMM out)
    float* bufB  = bufA + (size_t)N * 128;            // N*128 (agg out)
    int*   row_ptr = (int*)(bufB + (size_t)N * 128);  // N+1 ints
    int*   esrc    = row_ptr + (N + 1);               // E ints

    // CSR-build temporaries alias bufA (only used before first GEMM)
    int* deg       = (int*)bufA;          // N ints (later reused as cursor)
    int* blockSums = deg + N;             // ~512 ints
    int* blockOff  = blockSums + 512;     // ~512 ints

    float* sums  = stats;
    float* sumsq = stats + 128;
    float* scale = stats + 256;
    float* shift = stats + 384;

    const int BS = 256;
    dim3 blk(BS);
    const int NB = (N + 255) / 256;

    // ---- CSR build ----
    hipMemsetAsync(deg, 0, (size_t)N * 4, stream);
    deg_count_k<<<dim3((E + BS - 1) / BS), blk, 0, stream>>>(dst, deg, E);
    deg_to_dis_k<<<dim3(NB), blk, 0, stream>>>(deg, dis, N);
    scan_block_reduce_k<<<dim3(NB), blk, 0, stream>>>(deg, blockSums, N);
    scan_top_k<<<dim3(1), dim3(512), 0, stream>>>(blockSums, blockOff, row_ptr, NB, N, E);
    scan_final_k<<<dim3(NB), blk, 0, stream>>>(deg, blockOff, row_ptr, N);
    hipMemsetAsync(deg, 0, (size_t)N * 4, stream);  // deg -> cursor
    edge_scatter_k<<<dim3((E + BS - 1) / BS), blk, 0, stream>>>(src, dst, row_ptr, deg, esrc, E);

    const int gemm_grid = (N + 31) / 32;
    const int gat128 = (N + 7) / 8;
    const int gat64  = (N + 15) / 16;

    // ---- layer 1 ----
    gemm_k<128, false><<<dim3(gemm_grid), blk, 0, stream>>>(x, W1, nullptr, nullptr, bufA, N);
    hipMemsetAsync(stats, 0, 256 * 4, stream);
    gather_k<128, true><<<dim3(gat128), blk, 0, stream>>>(bufA, dis, b1, row_ptr, esrc,
                                                          bufB, sums, sumsq, N);
    bn_finalize_k<<<dim3(1), dim3(128), 0, stream>>>(sums, sumsq, g1, be1, scale, shift, N);

    // ---- layer 2 (BN applied inside GEMM staging) ----
    gemm_k<128, true><<<dim3(gemm_grid), blk, 0, stream>>>(bufB, W2, scale, shift, bufA, N);
    hipMemsetAsync(stats, 0, 256 * 4, stream);
    gather_k<128, true><<<dim3(gat128), blk, 0, stream>>>(bufA, dis, b2, row_ptr, esrc,
                                                          bufB, sums, sumsq, N);
    bn_finalize_k<<<dim3(1), dim3(128), 0, stream>>>(sums, sumsq, g2, be2, scale, shift, N);

    // ---- layer 3 (OUT = 64, straight to d_out) ----
    gemm_k<64, true><<<dim3(gemm_grid), blk, 0, stream>>>(bufB, W3, scale, shift, bufA, N);
    gather_k<64, false><<<dim3(gat64), blk, 0, stream>>>(bufA, dis, b3, row_ptr, esrc,
                                                         out, nullptr, nullptr, N);
}

// Round 3
// 767.688 us; speedup vs baseline: 9.1411x; 1.5987x over previous
//
#include <hip/hip_runtime.h>
#include <hip/hip_fp16.h>

// ---------------------------------------------------------------------------
// GCN 3-layer forward:  (GCNConv -> BN) x2 -> GCNConv
// N=100000, E=1600000, IN=H=128, OUT=64
// Round 2: f16 dis-prescaled rows for the gather (halves random-gather bytes,
//          kills per-edge dis[src] loads). CSR gather from round 1 retained.
// ---------------------------------------------------------------------------

static __device__ inline ushort f2h(float f) {
    union { __half h; ushort u; } cv;
    cv.h = __float2half_rn(f);
    return cv.u;
}
static __device__ inline float2 h2f2(unsigned int u) {
    union { unsigned int u; __half2 h; } cv;
    cv.u = u;
    return __half22float2(cv.h);
}

// ---------------- degree ----------------
__global__ void deg_count_k(const int* __restrict__ dst, int* __restrict__ deg, int E) {
    int i = blockIdx.x * blockDim.x + threadIdx.x;
    if (i < E) atomicAdd(&deg[dst[i]], 1);
}

__global__ void deg_to_dis_k(const int* __restrict__ deg, float* __restrict__ dis, int n) {
    int i = blockIdx.x * blockDim.x + threadIdx.x;
    if (i < n) dis[i] = rsqrtf((float)deg[i] + 1.0f);   // +1 self loop
}

// ---------------- CSR build: hierarchical exclusive scan of deg ------------
__global__ __launch_bounds__(256) void scan_block_reduce_k(const int* __restrict__ deg,
                                                           int* __restrict__ blockSums, int n) {
    __shared__ int tmp[256];
    int i = blockIdx.x * 256 + threadIdx.x;
    tmp[threadIdx.x] = (i < n) ? deg[i] : 0;
    __syncthreads();
    for (int off = 128; off > 0; off >>= 1) {
        if (threadIdx.x < off) tmp[threadIdx.x] += tmp[threadIdx.x + off];
        __syncthreads();
    }
    if (threadIdx.x == 0) blockSums[blockIdx.x] = tmp[0];
}

__global__ __launch_bounds__(512) void scan_top_k(int* __restrict__ blockSums,
                                                  int* __restrict__ blockOff,
                                                  int* __restrict__ row_ptr,
                                                  int nb, int n, int E) {
    __shared__ int tmp[512];
    int tid = threadIdx.x;
    int v = (tid < nb) ? blockSums[tid] : 0;
    tmp[tid] = v;
    __syncthreads();
    for (int off = 1; off < 512; off <<= 1) {
        int t = 0;
        if (tid >= off) t = tmp[tid - off];
        __syncthreads();
        tmp[tid] += t;
        __syncthreads();
    }
    if (tid < nb) blockOff[tid] = tmp[tid] - v;   // exclusive
    if (tid == 0) row_ptr[n] = E;
}

__global__ __launch_bounds__(256) void scan_final_k(const int* __restrict__ deg,
                                                    const int* __restrict__ blockOff,
                                                    int* __restrict__ row_ptr, int n) {
    __shared__ int tmp[256];
    int tid = threadIdx.x;
    int i = blockIdx.x * 256 + tid;
    int v = (i < n) ? deg[i] : 0;
    tmp[tid] = v;
    __syncthreads();
    for (int off = 1; off < 256; off <<= 1) {
        int t = 0;
        if (tid >= off) t = tmp[tid - off];
        __syncthreads();
        tmp[tid] += t;
        __syncthreads();
    }
    if (i < n) row_ptr[i] = blockOff[blockIdx.x] + tmp[tid] - v;   // exclusive
}

__global__ void edge_scatter_k(const int* __restrict__ src, const int* __restrict__ dst,
                               const int* __restrict__ row_ptr, int* __restrict__ cursor,
                               int* __restrict__ esrc, int E) {
    int e = blockIdx.x * blockDim.x + threadIdx.x;
    if (e >= E) return;
    int d = dst[e];
    int pos = row_ptr[d] + atomicAdd(&cursor[d], 1);
    esrc[pos] = src[e];
}

// ---------------- GEMM: Hs = f16( (BN(X) @ W) * dis )  --------------------
template <int OUTD, bool BNIN>
__global__ __launch_bounds__(256) void gemm_k(const float* __restrict__ X,
                                              const float* __restrict__ W,
                                              const float* __restrict__ scale,
                                              const float* __restrict__ shift,
                                              const float* __restrict__ dis,
                                              ushort* __restrict__ Hs, int n) {
    constexpr int K = 128;
    constexpr int ROWS = 32;
    constexpr int CQ = OUTD / 4;      // col quads per row: 32 or 16
    constexpr int TR = 256 / CQ;      // thread groups along rows: 8 or 16
    constexpr int RPT = ROWS / TR;    // rows per thread: 4 or 2

    __shared__ float ws[K * OUTD];
    __shared__ float xs[ROWS][K];

    const int tx = threadIdx.x;

    // stage W
    {
        const float4* W4 = (const float4*)W;
        float4* ws4 = (float4*)ws;
        constexpr int tot = K * OUTD / 4;
        for (int i = tx; i < tot; i += 256) ws4[i] = W4[i];
    }
    // stage X tile (ROWS x K), BN applied on the fly
    const int row0 = blockIdx.x * ROWS;
    {
        const float4* X4 = (const float4*)X;
        constexpr int tot = ROWS * K / 4;  // 1024
        for (int i = tx; i < tot; i += 256) {
            int r = i / (K / 4);
            int kk = i - r * (K / 4);
            int gr = row0 + r;
            float4 v = make_float4(0.f, 0.f, 0.f, 0.f);
            if (gr < n) {
                v = X4[(size_t)gr * (K / 4) + kk];
                if (BNIN) {
                    float4 sc = ((const float4*)scale)[kk];
                    float4 sh = ((const float4*)shift)[kk];
                    v.x = v.x * sc.x + sh.x;
                    v.y = v.y * sc.y + sh.y;
                    v.z = v.z * sc.z + sh.z;
                    v.w = v.w * sc.w + sh.w;
                }
            }
            ((float4*)&xs[r][0])[kk] = v;
        }
    }
    __syncthreads();

    const int cq = tx % CQ;
    const int tr = tx / CQ;

    float acc[RPT][4];
#pragma unroll
    for (int r = 0; r < RPT; ++r)
#pragma unroll
        for (int c = 0; c < 4; ++c) acc[r][c] = 0.f;

#pragma unroll 8
    for (int k = 0; k < K; ++k) {
        float4 wv = ((const float4*)(&ws[k * OUTD]))[cq];
#pragma unroll
        for (int r = 0; r < RPT; ++r) {
            float xv = xs[tr * RPT + r][k];
            acc[r][0] += xv * wv.x;
            acc[r][1] += xv * wv.y;
            acc[r][2] += xv * wv.z;
            acc[r][3] += xv * wv.w;
        }
    }

#pragma unroll
    for (int r = 0; r < RPT; ++r) {
        int gr = row0 + tr * RPT + r;
        if (gr < n) {
            float dd = dis[gr];
            ushort4 pk;
            pk.x = f2h(acc[r][0] * dd);
            pk.y = f2h(acc[r][1] * dd);
            pk.z = f2h(acc[r][2] * dd);
            pk.w = f2h(acc[r][3] * dd);
            ((ushort4*)&Hs[(size_t)gr * OUTD])[cq] = pk;
        }
    }
}

// ---------------- gather aggregation (+ optional fused BN stats) -----------
// O[i] = dis[i] * ( Hs[i] + sum_{e: dst=i} Hs[src_e] ) + b
// where Hs = f16(h * dis) row-major [N][OUTD].
template <int OUTD, bool STATS>
__global__ __launch_bounds__(256) void gather_k(const ushort* __restrict__ Hs,
                                                const float* __restrict__ dis,
                                                const float* __restrict__ b,
                                                const int* __restrict__ row_ptr,
                                                const int* __restrict__ esrc,
                                                float* __restrict__ O,
                                                float* __restrict__ sums,
                                                float* __restrict__ sumsq, int n) {
    constexpr int LPR = OUTD / 8;        // lanes per row (uint4 = 8 f16 each): 16 or 8
    constexpr int GROUPS = 256 / LPR;    // nodes per block: 16 or 32

    __shared__ float s_sum[STATS ? OUTD : 1];
    __shared__ float s_sq[STATS ? OUTD : 1];
    if (STATS) {
        if (threadIdx.x < OUTD) { s_sum[threadIdx.x] = 0.f; s_sq[threadIdx.x] = 0.f; }
        __syncthreads();
    }

    const int g = threadIdx.x / LPR;
    const int lane = threadIdx.x % LPR;
    const int node = blockIdx.x * GROUPS + g;
    const bool active = node < n;

    float acc[8];
#pragma unroll
    for (int c = 0; c < 8; ++c) acc[c] = 0.f;

    float o[8];
#pragma unroll
    for (int c = 0; c < 8; ++c) o[c] = 0.f;

    if (active) {
        const uint4* H4 = (const uint4*)Hs;
        const size_t lofs = lane;

        // self row (dis already folded into Hs; outer dis[node] applied below)
        {
            uint4 v = H4[(size_t)node * LPR + lofs];
            float2 f;
            f = h2f2(v.x); acc[0] += f.x; acc[1] += f.y;
            f = h2f2(v.y); acc[2] += f.x; acc[3] += f.y;
            f = h2f2(v.z); acc[4] += f.x; acc[5] += f.y;
            f = h2f2(v.w); acc[6] += f.x; acc[7] += f.y;
        }
        int beg = row_ptr[node];
        int end = row_ptr[node + 1];
        for (int j = beg; j < end; ++j) {
            int s = esrc[j];
            uint4 v = H4[(size_t)s * LPR + lofs];
            float2 f;
            f = h2f2(v.x); acc[0] += f.x; acc[1] += f.y;
            f = h2f2(v.y); acc[2] += f.x; acc[3] += f.y;
            f = h2f2(v.z); acc[4] += f.x; acc[5] += f.y;
            f = h2f2(v.w); acc[6] += f.x; acc[7] += f.y;
        }

        float dd = dis[node];
        float4 b0 = ((const float4*)b)[lane * 2 + 0];
        float4 b1 = ((const float4*)b)[lane * 2 + 1];
        o[0] = acc[0] * dd + b0.x;
        o[1] = acc[1] * dd + b0.y;
        o[2] = acc[2] * dd + b0.z;
        o[3] = acc[3] * dd + b0.w;
        o[4] = acc[4] * dd + b1.x;
        o[5] = acc[5] * dd + b1.y;
        o[6] = acc[6] * dd + b1.z;
        o[7] = acc[7] * dd + b1.w;

        float4* O4 = (float4*)O;
        size_t base = (size_t)node * (OUTD / 4) + lane * 2;
        O4[base + 0] = make_float4(o[0], o[1], o[2], o[3]);
        O4[base + 1] = make_float4(o[4], o[5], o[6], o[7]);
    }

    if (STATS) {
        // LPR == 16 here: lanes {l, l^16, l^32, l^48} of a wave hold the same
        // columns for 4 different nodes -> butterfly-reduce across groups.
        float sv[8], qv[8];
#pragma unroll
        for (int c = 0; c < 8; ++c) { sv[c] = o[c]; qv[c] = o[c] * o[c]; }
#pragma unroll
        for (int c = 0; c < 8; ++c) {
            sv[c] += __shfl_xor(sv[c], 16);
            sv[c] += __shfl_xor(sv[c], 32);
            qv[c] += __shfl_xor(qv[c], 16);
            qv[c] += __shfl_xor(qv[c], 32);
        }
        if ((threadIdx.x & 63) < 16) {
            int col0 = lane * 8;
#pragma unroll
            for (int c = 0; c < 8; ++c) {
                atomicAdd(&s_sum[col0 + c], sv[c]);
                atomicAdd(&s_sq[col0 + c], qv[c]);
            }
        }
        __syncthreads();
        if (threadIdx.x < OUTD) {
            atomicAdd(&sums[threadIdx.x], s_sum[threadIdx.x]);
            atomicAdd(&sumsq[threadIdx.x], s_sq[threadIdx.x]);
        }
    }
}

// ---------------- BN finalize: scale/shift from sums ----------------------
__global__ void bn_finalize_k(const float* __restrict__ sums, const float* __restrict__ sumsq,
                              const float* __restrict__ g, const float* __restrict__ be,
                              float* __restrict__ scale, float* __restrict__ shift, int n) {
    int c = threadIdx.x;  // 128 threads
    float inv_n = 1.0f / (float)n;
    float m = sums[c] * inv_n;
    float v = sumsq[c] * inv_n - m * m;
    float sc = rsqrtf(v + 1e-5f) * g[c];
    scale[c] = sc;
    shift[c] = be[c] - m * sc;
}

// ---------------------------------------------------------------------------
extern "C" void kernel_launch(void* const* d_in, const int* in_sizes, int n_in,
                              void* d_out, int out_size, void* d_ws, size_t ws_size,
                              hipStream_t stream) {
    const float* x   = (const float*)d_in[0];
    const int*   ei  = (const int*)d_in[1];
    const float* W1  = (const float*)d_in[2];
    const float* b1  = (const float*)d_in[3];
    const float* g1  = (const float*)d_in[4];
    const float* be1 = (const float*)d_in[5];
    const float* W2  = (const float*)d_in[6];
    const float* b2  = (const float*)d_in[7];
    const float* g2  = (const float*)d_in[8];
    const float* be2 = (const float*)d_in[9];
    const float* W3  = (const float*)d_in[10];
    const float* b3  = (const float*)d_in[11];
    float* out = (float*)d_out;

    const int N = in_sizes[0] / 128;
    const int E = in_sizes[1] / 2;
    const int* src = ei;
    const int* dst = ei + E;

    // ---- workspace layout (persistent) ----
    float* wsp   = (float*)d_ws;
    float* dis   = wsp;                               // N floats
    float* stats = wsp + N;                           // 512 floats
    float* bufA  = stats + 512;                       // N*128 f32 region; Hs (f16) lives here
    float* bufB  = bufA + (size_t)N * 128;            // N*128 f32 (agg out)
    int*   row_ptr = (int*)(bufB + (size_t)N * 128);  // N+1 ints
    int*   esrc    = row_ptr + (N + 1);               // E ints

    ushort* Hs = (ushort*)bufA;                       // N*128 f16

    // CSR-build temporaries alias bufA (only used before first GEMM)
    int* deg       = (int*)bufA;          // N ints (later reused as cursor)
    int* blockSums = deg + N;             // ~512 ints
    int* blockOff  = blockSums + 512;     // ~512 ints

    float* sums  = stats;
    float* sumsq = stats + 128;
    float* scale = stats + 256;
    float* shift = stats + 384;

    const int BS = 256;
    dim3 blk(BS);
    const int NB = (N + 255) / 256;

    // ---- CSR build ----
    hipMemsetAsync(deg, 0, (size_t)N * 4, stream);
    deg_count_k<<<dim3((E + BS - 1) / BS), blk, 0, stream>>>(dst, deg, E);
    deg_to_dis_k<<<dim3(NB), blk, 0, stream>>>(deg, dis, N);
    scan_block_reduce_k<<<dim3(NB), blk, 0, stream>>>(deg, blockSums, N);
    scan_top_k<<<dim3(1), dim3(512), 0, stream>>>(blockSums, blockOff, row_ptr, NB, N, E);
    scan_final_k<<<dim3(NB), blk, 0, stream>>>(deg, blockOff, row_ptr, N);
    hipMemsetAsync(deg, 0, (size_t)N * 4, stream);  // deg -> cursor
    edge_scatter_k<<<dim3((E + BS - 1) / BS), blk, 0, stream>>>(src, dst, row_ptr, deg, esrc, E);

    const int gemm_grid = (N + 31) / 32;
    const int gat128 = (N + 15) / 16;   // GROUPS=16
    const int gat64  = (N + 31) / 32;   // GROUPS=32

    // ---- layer 1 ----
    gemm_k<128, false><<<dim3(gemm_grid), blk, 0, stream>>>(x, W1, nullptr, nullptr, dis, Hs, N);
    hipMemsetAsync(stats, 0, 256 * 4, stream);
    gather_k<128, true><<<dim3(gat128), blk, 0, stream>>>(Hs, dis, b1, row_ptr, esrc,
                                                          bufB, sums, sumsq, N);
    bn_finalize_k<<<dim3(1), dim3(128), 0, stream>>>(sums, sumsq, g1, be1, scale, shift, N);

    // ---- layer 2 (BN applied inside GEMM staging) ----
    gemm_k<128, true><<<dim3(gemm_grid), blk, 0, stream>>>(bufB, W2, scale, shift, dis, Hs, N);
    hipMemsetAsync(stats, 0, 256 * 4, stream);
    gather_k<128, true><<<dim3(gat128), blk, 0, stream>>>(Hs, dis, b2, row_ptr, esrc,
                                                          bufB, sums, sumsq, N);
    bn_finalize_k<<<dim3(1), dim3(128), 0, stream>>>(sums, sumsq, g2, be2, scale, shift, N);

    // ---- layer 3 (OUT = 64, straight to d_out) ----
    gemm_k<64, true><<<dim3(gemm_grid), blk, 0, stream>>>(bufB, W3, scale, shift, dis, Hs, N);
    gather_k<64, false><<<dim3(gat64), blk, 0, stream>>>(Hs, dis, b3, row_ptr, esrc,
                                                         out, nullptr, nullptr, N);
}

// Round 4
// 747.077 us; speedup vs baseline: 9.3933x; 1.0276x over previous
//
#include <hip/hip_runtime.h>
#include <hip/hip_fp16.h>

// ---------------------------------------------------------------------------
// GCN 3-layer forward:  (GCNConv -> BN) x2 -> GCNConv
// N=100000, E=1600000, IN=H=128, OUT=64
// Round 3: feature-chunked XCD-affine gather. Hs stored chunk-major
//          [NCHUNK][N][16 f16] so each chunk (3.2 MB) is L2-resident per XCD;
//          chunk = blockIdx & (NCHUNK-1) rides the round-robin XCD dispatch.
// ---------------------------------------------------------------------------

static __device__ inline ushort f2h(float f) {
    union { __half h; ushort u; } cv;
    cv.h = __float2half_rn(f);
    return cv.u;
}
static __device__ inline float2 h2f2(unsigned int u) {
    union { unsigned int u; __half2 h; } cv;
    cv.u = u;
    return __half22float2(cv.h);
}

// ---------------- degree ----------------
__global__ void deg_count_k(const int* __restrict__ dst, int* __restrict__ deg, int E) {
    int i = blockIdx.x * blockDim.x + threadIdx.x;
    if (i < E) atomicAdd(&deg[dst[i]], 1);
}

__global__ void deg_to_dis_k(const int* __restrict__ deg, float* __restrict__ dis, int n) {
    int i = blockIdx.x * blockDim.x + threadIdx.x;
    if (i < n) dis[i] = rsqrtf((float)deg[i] + 1.0f);   // +1 self loop
}

// ---------------- CSR build: hierarchical exclusive scan of deg ------------
__global__ __launch_bounds__(256) void scan_block_reduce_k(const int* __restrict__ deg,
                                                           int* __restrict__ blockSums, int n) {
    __shared__ int tmp[256];
    int i = blockIdx.x * 256 + threadIdx.x;
    tmp[threadIdx.x] = (i < n) ? deg[i] : 0;
    __syncthreads();
    for (int off = 128; off > 0; off >>= 1) {
        if (threadIdx.x < off) tmp[threadIdx.x] += tmp[threadIdx.x + off];
        __syncthreads();
    }
    if (threadIdx.x == 0) blockSums[blockIdx.x] = tmp[0];
}

__global__ __launch_bounds__(512) void scan_top_k(int* __restrict__ blockSums,
                                                  int* __restrict__ blockOff,
                                                  int* __restrict__ row_ptr,
                                                  int nb, int n, int E) {
    __shared__ int tmp[512];
    int tid = threadIdx.x;
    int v = (tid < nb) ? blockSums[tid] : 0;
    tmp[tid] = v;
    __syncthreads();
    for (int off = 1; off < 512; off <<= 1) {
        int t = 0;
        if (tid >= off) t = tmp[tid - off];
        __syncthreads();
        tmp[tid] += t;
        __syncthreads();
    }
    if (tid < nb) blockOff[tid] = tmp[tid] - v;   // exclusive
    if (tid == 0) row_ptr[n] = E;
}

__global__ __launch_bounds__(256) void scan_final_k(const int* __restrict__ deg,
                                                    const int* __restrict__ blockOff,
                                                    int* __restrict__ row_ptr, int n) {
    __shared__ int tmp[256];
    int tid = threadIdx.x;
    int i = blockIdx.x * 256 + tid;
    int v = (i < n) ? deg[i] : 0;
    tmp[tid] = v;
    __syncthreads();
    for (int off = 1; off < 256; off <<= 1) {
        int t = 0;
        if (tid >= off) t = tmp[tid - off];
        __syncthreads();
        tmp[tid] += t;
        __syncthreads();
    }
    if (i < n) row_ptr[i] = blockOff[blockIdx.x] + tmp[tid] - v;   // exclusive
}

__global__ void edge_scatter_k(const int* __restrict__ src, const int* __restrict__ dst,
                               const int* __restrict__ row_ptr, int* __restrict__ cursor,
                               int* __restrict__ esrc, int E) {
    int e = blockIdx.x * blockDim.x + threadIdx.x;
    if (e >= E) return;
    int d = dst[e];
    int pos = row_ptr[d] + atomicAdd(&cursor[d], 1);
    esrc[pos] = src[e];
}

// ------- GEMM: Hs = f16( (BN(X) @ W) * dis ), chunk-major output ----------
// Hs layout: [NCHUNK][N][16 f16], chunk c holds columns [16c, 16c+16).
template <int OUTD, bool BNIN>
__global__ __launch_bounds__(256) void gemm_k(const float* __restrict__ X,
                                              const float* __restrict__ W,
                                              const float* __restrict__ scale,
                                              const float* __restrict__ shift,
                                              const float* __restrict__ dis,
                                              ushort* __restrict__ Hs, int n) {
    constexpr int K = 128;
    constexpr int ROWS = 32;
    constexpr int CQ = OUTD / 4;      // col quads per row: 32 or 16
    constexpr int TR = 256 / CQ;      // thread groups along rows: 8 or 16
    constexpr int RPT = ROWS / TR;    // rows per thread: 4 or 2

    __shared__ float ws[K * OUTD];
    __shared__ float xs[ROWS][K];

    const int tx = threadIdx.x;

    // stage W
    {
        const float4* W4 = (const float4*)W;
        float4* ws4 = (float4*)ws;
        constexpr int tot = K * OUTD / 4;
        for (int i = tx; i < tot; i += 256) ws4[i] = W4[i];
    }
    // stage X tile (ROWS x K), BN applied on the fly
    const int row0 = blockIdx.x * ROWS;
    {
        const float4* X4 = (const float4*)X;
        constexpr int tot = ROWS * K / 4;  // 1024
        for (int i = tx; i < tot; i += 256) {
            int r = i / (K / 4);
            int kk = i - r * (K / 4);
            int gr = row0 + r;
            float4 v = make_float4(0.f, 0.f, 0.f, 0.f);
            if (gr < n) {
                v = X4[(size_t)gr * (K / 4) + kk];
                if (BNIN) {
                    float4 sc = ((const float4*)scale)[kk];
                    float4 sh = ((const float4*)shift)[kk];
                    v.x = v.x * sc.x + sh.x;
                    v.y = v.y * sc.y + sh.y;
                    v.z = v.z * sc.z + sh.z;
                    v.w = v.w * sc.w + sh.w;
                }
            }
            ((float4*)&xs[r][0])[kk] = v;
        }
    }
    __syncthreads();

    const int cq = tx % CQ;
    const int tr = tx / CQ;

    float acc[RPT][4];
#pragma unroll
    for (int r = 0; r < RPT; ++r)
#pragma unroll
        for (int c = 0; c < 4; ++c) acc[r][c] = 0.f;

#pragma unroll 8
    for (int k = 0; k < K; ++k) {
        float4 wv = ((const float4*)(&ws[k * OUTD]))[cq];
#pragma unroll
        for (int r = 0; r < RPT; ++r) {
            float xv = xs[tr * RPT + r][k];
            acc[r][0] += xv * wv.x;
            acc[r][1] += xv * wv.y;
            acc[r][2] += xv * wv.z;
            acc[r][3] += xv * wv.w;
        }
    }

    const int c = cq >> 2;          // chunk index
    const int qin = cq & 3;         // quad within chunk
#pragma unroll
    for (int r = 0; r < RPT; ++r) {
        int gr = row0 + tr * RPT + r;
        if (gr < n) {
            float dd = dis[gr];
            ushort4 pk;
            pk.x = f2h(acc[r][0] * dd);
            pk.y = f2h(acc[r][1] * dd);
            pk.z = f2h(acc[r][2] * dd);
            pk.w = f2h(acc[r][3] * dd);
            // chunk-major: [(c*n + gr)*16 + qin*4] ushorts
            ((ushort4*)Hs)[((size_t)c * n + gr) * 4 + qin] = pk;
        }
    }
}

// ---------------- chunked gather aggregation (+ fused BN stats) ------------
// Per chunk c (16 cols): O[i][16c..16c+16) = dis[i]*(Hs_c[i] + sum Hs_c[src]) + b
// chunk = blockIdx & (NCHUNK-1) -> rides round-robin XCD dispatch so each
// XCD's L2 holds one 3.2 MB chunk.
template <int OUTD, bool STATS>
__global__ __launch_bounds__(256) void gather_k(const ushort* __restrict__ Hs,
                                                const float* __restrict__ dis,
                                                const float* __restrict__ b,
                                                const int* __restrict__ row_ptr,
                                                const int* __restrict__ esrc,
                                                float* __restrict__ O,
                                                float* __restrict__ sums,
                                                float* __restrict__ sumsq, int n) {
    constexpr int NCHUNK = OUTD / 16;

    __shared__ float s_sum[16];
    __shared__ float s_sq[16];
    if (STATS) {
        if (threadIdx.x < 16) { s_sum[threadIdx.x] = 0.f; s_sq[threadIdx.x] = 0.f; }
        __syncthreads();
    }

    const int chunk = blockIdx.x & (NCHUNK - 1);
    const int nblk  = blockIdx.x / NCHUNK;
    const int g     = threadIdx.x >> 1;     // node within block: 0..127
    const int lane  = threadIdx.x & 1;      // which uint4 (8 f16) of the 32B row
    const int node  = nblk * 128 + g;

    float o[8];
#pragma unroll
    for (int c = 0; c < 8; ++c) o[c] = 0.f;

    if (node < n) {
        const uint4* Hc = (const uint4*)Hs + (size_t)chunk * n * 2;

        float acc[8];
        {   // self row (dis pre-folded into Hs)
            uint4 v = Hc[(size_t)node * 2 + lane];
            float2 f;
            f = h2f2(v.x); acc[0] = f.x; acc[1] = f.y;
            f = h2f2(v.y); acc[2] = f.x; acc[3] = f.y;
            f = h2f2(v.z); acc[4] = f.x; acc[5] = f.y;
            f = h2f2(v.w); acc[6] = f.x; acc[7] = f.y;
        }
        int beg = row_ptr[node];
        int end = row_ptr[node + 1];
        for (int j = beg; j < end; ++j) {
            int s = esrc[j];
            uint4 v = Hc[(size_t)s * 2 + lane];
            float2 f;
            f = h2f2(v.x); acc[0] += f.x; acc[1] += f.y;
            f = h2f2(v.y); acc[2] += f.x; acc[3] += f.y;
            f = h2f2(v.z); acc[4] += f.x; acc[5] += f.y;
            f = h2f2(v.w); acc[6] += f.x; acc[7] += f.y;
        }

        float dd = dis[node];
        const float4* B4 = (const float4*)b + chunk * 4 + lane * 2;
        float4 b0 = B4[0];
        float4 b1 = B4[1];
        o[0] = acc[0] * dd + b0.x;
        o[1] = acc[1] * dd + b0.y;
        o[2] = acc[2] * dd + b0.z;
        o[3] = acc[3] * dd + b0.w;
        o[4] = acc[4] * dd + b1.x;
        o[5] = acc[5] * dd + b1.y;
        o[6] = acc[6] * dd + b1.z;
        o[7] = acc[7] * dd + b1.w;

        float4* O4 = (float4*)O + (size_t)node * (OUTD / 4) + chunk * 4 + lane * 2;
        O4[0] = make_float4(o[0], o[1], o[2], o[3]);
        O4[1] = make_float4(o[4], o[5], o[6], o[7]);
    }

    if (STATS) {
        // lanes of equal parity (lane&1) hold the same 8 columns for 32 nodes
        float sv[8], qv[8];
#pragma unroll
        for (int c = 0; c < 8; ++c) { sv[c] = o[c]; qv[c] = o[c] * o[c]; }
#pragma unroll
        for (int c = 0; c < 8; ++c) {
#pragma unroll
            for (int m = 2; m <= 32; m <<= 1) {
                sv[c] += __shfl_xor(sv[c], m);
                qv[c] += __shfl_xor(qv[c], m);
            }
        }
        if ((threadIdx.x & 63) < 2) {
            int col0 = lane * 8;
#pragma unroll
            for (int c = 0; c < 8; ++c) {
                atomicAdd(&s_sum[col0 + c], sv[c]);
                atomicAdd(&s_sq[col0 + c], qv[c]);
            }
        }
        __syncthreads();
        if (threadIdx.x < 16) {
            atomicAdd(&sums[chunk * 16 + threadIdx.x], s_sum[threadIdx.x]);
            atomicAdd(&sumsq[chunk * 16 + threadIdx.x], s_sq[threadIdx.x]);
        }
    }
}

// ---------------- BN finalize: scale/shift from sums ----------------------
__global__ void bn_finalize_k(const float* __restrict__ sums, const float* __restrict__ sumsq,
                              const float* __restrict__ g, const float* __restrict__ be,
                              float* __restrict__ scale, float* __restrict__ shift, int n) {
    int c = threadIdx.x;  // 128 threads
    float inv_n = 1.0f / (float)n;
    float m = sums[c] * inv_n;
    float v = sumsq[c] * inv_n - m * m;
    float sc = rsqrtf(v + 1e-5f) * g[c];
    scale[c] = sc;
    shift[c] = be[c] - m * sc;
}

// ---------------------------------------------------------------------------
extern "C" void kernel_launch(void* const* d_in, const int* in_sizes, int n_in,
                              void* d_out, int out_size, void* d_ws, size_t ws_size,
                              hipStream_t stream) {
    const float* x   = (const float*)d_in[0];
    const int*   ei  = (const int*)d_in[1];
    const float* W1  = (const float*)d_in[2];
    const float* b1  = (const float*)d_in[3];
    const float* g1  = (const float*)d_in[4];
    const float* be1 = (const float*)d_in[5];
    const float* W2  = (const float*)d_in[6];
    const float* b2  = (const float*)d_in[7];
    const float* g2  = (const float*)d_in[8];
    const float* be2 = (const float*)d_in[9];
    const float* W3  = (const float*)d_in[10];
    const float* b3  = (const float*)d_in[11];
    float* out = (float*)d_out;

    const int N = in_sizes[0] / 128;
    const int E = in_sizes[1] / 2;
    const int* src = ei;
    const int* dst = ei + E;

    // ---- workspace layout (persistent) ----
    float* wsp   = (float*)d_ws;
    float* dis   = wsp;                               // N floats
    float* stats = wsp + N;                           // 512 floats
    float* bufA  = stats + 512;                       // N*128 f32 region; Hs (f16) lives here
    float* bufB  = bufA + (size_t)N * 128;            // N*128 f32 (agg out)
    int*   row_ptr = (int*)(bufB + (size_t)N * 128);  // N+1 ints
    int*   esrc    = row_ptr + (N + 1);               // E ints

    ushort* Hs = (ushort*)bufA;                       // [NCHUNK][N][16] f16

    // CSR-build temporaries alias bufA (only used before first GEMM)
    int* deg       = (int*)bufA;          // N ints (later reused as cursor)
    int* blockSums = deg + N;             // ~512 ints
    int* blockOff  = blockSums + 512;     // ~512 ints

    float* sums  = stats;
    float* sumsq = stats + 128;
    float* scale = stats + 256;
    float* shift = stats + 384;

    const int BS = 256;
    dim3 blk(BS);
    const int NB = (N + 255) / 256;

    // ---- CSR build ----
    hipMemsetAsync(deg, 0, (size_t)N * 4, stream);
    deg_count_k<<<dim3((E + BS - 1) / BS), blk, 0, stream>>>(dst, deg, E);
    deg_to_dis_k<<<dim3(NB), blk, 0, stream>>>(deg, dis, N);
    scan_block_reduce_k<<<dim3(NB), blk, 0, stream>>>(deg, blockSums, N);
    scan_top_k<<<dim3(1), dim3(512), 0, stream>>>(blockSums, blockOff, row_ptr, NB, N, E);
    scan_final_k<<<dim3(NB), blk, 0, stream>>>(deg, blockOff, row_ptr, N);
    hipMemsetAsync(deg, 0, (size_t)N * 4, stream);  // deg -> cursor
    edge_scatter_k<<<dim3((E + BS - 1) / BS), blk, 0, stream>>>(src, dst, row_ptr, deg, esrc, E);

    const int gemm_grid = (N + 31) / 32;
    const int NBg = (N + 127) / 128;    // gather node-blocks (128 nodes/block)

    // ---- layer 1 ----
    gemm_k<128, false><<<dim3(gemm_grid), blk, 0, stream>>>(x, W1, nullptr, nullptr, dis, Hs, N);
    hipMemsetAsync(stats, 0, 256 * 4, stream);
    gather_k<128, true><<<dim3(NBg * 8), blk, 0, stream>>>(Hs, dis, b1, row_ptr, esrc,
                                                           bufB, sums, sumsq, N);
    bn_finalize_k<<<dim3(1), dim3(128), 0, stream>>>(sums, sumsq, g1, be1, scale, shift, N);

    // ---- layer 2 (BN applied inside GEMM staging) ----
    gemm_k<128, true><<<dim3(gemm_grid), blk, 0, stream>>>(bufB, W2, scale, shift, dis, Hs, N);
    hipMemsetAsync(stats, 0, 256 * 4, stream);
    gather_k<128, true><<<dim3(NBg * 8), blk, 0, stream>>>(Hs, dis, b2, row_ptr, esrc,
                                                           bufB, sums, sumsq, N);
    bn_finalize_k<<<dim3(1), dim3(128), 0, stream>>>(sums, sumsq, g2, be2, scale, shift, N);

    // ---- layer 3 (OUT = 64, straight to d_out) ----
    gemm_k<64, true><<<dim3(gemm_grid), blk, 0, stream>>>(bufB, W3, scale, shift, dis, Hs, N);
    gather_k<64, false><<<dim3(NBg * 4), blk, 0, stream>>>(Hs, dis, b3, row_ptr, esrc,
                                                           out, nullptr, nullptr, N);
}

// Round 5
// 569.488 us; speedup vs baseline: 12.3225x; 1.3118x over previous
//
#include <hip/hip_runtime.h>
#include <hip/hip_fp16.h>

// ---------------------------------------------------------------------------
// GCN 3-layer forward:  (GCNConv -> BN) x2 -> GCNConv
// N=100000, E=1600000, IN=H=128, OUT=64
// Round 4: 32-col chunks (64B rows, full cache-line utilization, half the
//          edge passes) + software-pipelined unroll-4 gather loop for MLP.
// ---------------------------------------------------------------------------

static __device__ inline ushort f2h(float f) {
    union { __half h; ushort u; } cv;
    cv.h = __float2half_rn(f);
    return cv.u;
}
static __device__ inline float2 h2f2(unsigned int u) {
    union { unsigned int u; __half2 h; } cv;
    cv.u = u;
    return __half22float2(cv.h);
}

#define ACC8(base, v) do { float2 _f; \
    _f = h2f2((v).x); acc[(base)+0] += _f.x; acc[(base)+1] += _f.y; \
    _f = h2f2((v).y); acc[(base)+2] += _f.x; acc[(base)+3] += _f.y; \
    _f = h2f2((v).z); acc[(base)+4] += _f.x; acc[(base)+5] += _f.y; \
    _f = h2f2((v).w); acc[(base)+6] += _f.x; acc[(base)+7] += _f.y; \
} while (0)

// ---------------- degree ----------------
__global__ void deg_count_k(const int* __restrict__ dst, int* __restrict__ deg, int E) {
    int i = blockIdx.x * blockDim.x + threadIdx.x;
    if (i < E) atomicAdd(&deg[dst[i]], 1);
}

__global__ void deg_to_dis_k(const int* __restrict__ deg, float* __restrict__ dis, int n) {
    int i = blockIdx.x * blockDim.x + threadIdx.x;
    if (i < n) dis[i] = rsqrtf((float)deg[i] + 1.0f);   // +1 self loop
}

// ---------------- CSR build: hierarchical exclusive scan of deg ------------
__global__ __launch_bounds__(256) void scan_block_reduce_k(const int* __restrict__ deg,
                                                           int* __restrict__ blockSums, int n) {
    __shared__ int tmp[256];
    int i = blockIdx.x * 256 + threadIdx.x;
    tmp[threadIdx.x] = (i < n) ? deg[i] : 0;
    __syncthreads();
    for (int off = 128; off > 0; off >>= 1) {
        if (threadIdx.x < off) tmp[threadIdx.x] += tmp[threadIdx.x + off];
        __syncthreads();
    }
    if (threadIdx.x == 0) blockSums[blockIdx.x] = tmp[0];
}

__global__ __launch_bounds__(512) void scan_top_k(int* __restrict__ blockSums,
                                                  int* __restrict__ blockOff,
                                                  int* __restrict__ row_ptr,
                                                  int nb, int n, int E) {
    __shared__ int tmp[512];
    int tid = threadIdx.x;
    int v = (tid < nb) ? blockSums[tid] : 0;
    tmp[tid] = v;
    __syncthreads();
    for (int off = 1; off < 512; off <<= 1) {
        int t = 0;
        if (tid >= off) t = tmp[tid - off];
        __syncthreads();
        tmp[tid] += t;
        __syncthreads();
    }
    if (tid < nb) blockOff[tid] = tmp[tid] - v;   // exclusive
    if (tid == 0) row_ptr[n] = E;
}

__global__ __launch_bounds__(256) void scan_final_k(const int* __restrict__ deg,
                                                    const int* __restrict__ blockOff,
                                                    int* __restrict__ row_ptr, int n) {
    __shared__ int tmp[256];
    int tid = threadIdx.x;
    int i = blockIdx.x * 256 + tid;
    int v = (i < n) ? deg[i] : 0;
    tmp[tid] = v;
    __syncthreads();
    for (int off = 1; off < 256; off <<= 1) {
        int t = 0;
        if (tid >= off) t = tmp[tid - off];
        __syncthreads();
        tmp[tid] += t;
        __syncthreads();
    }
    if (i < n) row_ptr[i] = blockOff[blockIdx.x] + tmp[tid] - v;   // exclusive
}

__global__ void edge_scatter_k(const int* __restrict__ src, const int* __restrict__ dst,
                               const int* __restrict__ row_ptr, int* __restrict__ cursor,
                               int* __restrict__ esrc, int E) {
    int e = blockIdx.x * blockDim.x + threadIdx.x;
    if (e >= E) return;
    int d = dst[e];
    int pos = row_ptr[d] + atomicAdd(&cursor[d], 1);
    esrc[pos] = src[e];
}

// ------- GEMM: Hs = f16( (BN(X) @ W) * dis ), chunk-major output ----------
// Hs layout: [NCHUNK][N][32 f16], chunk c holds columns [32c, 32c+32).
template <int OUTD, bool BNIN>
__global__ __launch_bounds__(256) void gemm_k(const float* __restrict__ X,
                                              const float* __restrict__ W,
                                              const float* __restrict__ scale,
                                              const float* __restrict__ shift,
                                              const float* __restrict__ dis,
                                              ushort* __restrict__ Hs, int n) {
    constexpr int K = 128;
    constexpr int ROWS = 32;
    constexpr int CQ = OUTD / 4;      // col quads per row: 32 or 16
    constexpr int TR = 256 / CQ;      // thread groups along rows: 8 or 16
    constexpr int RPT = ROWS / TR;    // rows per thread: 4 or 2

    __shared__ float ws[K * OUTD];
    __shared__ float xs[ROWS][K];

    const int tx = threadIdx.x;

    // stage W
    {
        const float4* W4 = (const float4*)W;
        float4* ws4 = (float4*)ws;
        constexpr int tot = K * OUTD / 4;
        for (int i = tx; i < tot; i += 256) ws4[i] = W4[i];
    }
    // stage X tile (ROWS x K), BN applied on the fly
    const int row0 = blockIdx.x * ROWS;
    {
        const float4* X4 = (const float4*)X;
        constexpr int tot = ROWS * K / 4;  // 1024
        for (int i = tx; i < tot; i += 256) {
            int r = i / (K / 4);
            int kk = i - r * (K / 4);
            int gr = row0 + r;
            float4 v = make_float4(0.f, 0.f, 0.f, 0.f);
            if (gr < n) {
                v = X4[(size_t)gr * (K / 4) + kk];
                if (BNIN) {
                    float4 sc = ((const float4*)scale)[kk];
                    float4 sh = ((const float4*)shift)[kk];
                    v.x = v.x * sc.x + sh.x;
                    v.y = v.y * sc.y + sh.y;
                    v.z = v.z * sc.z + sh.z;
                    v.w = v.w * sc.w + sh.w;
                }
            }
            ((float4*)&xs[r][0])[kk] = v;
        }
    }
    __syncthreads();

    const int cq = tx % CQ;
    const int tr = tx / CQ;

    float acc[RPT][4];
#pragma unroll
    for (int r = 0; r < RPT; ++r)
#pragma unroll
        for (int c = 0; c < 4; ++c) acc[r][c] = 0.f;

#pragma unroll 8
    for (int k = 0; k < K; ++k) {
        float4 wv = ((const float4*)(&ws[k * OUTD]))[cq];
#pragma unroll
        for (int r = 0; r < RPT; ++r) {
            float xv = xs[tr * RPT + r][k];
            acc[r][0] += xv * wv.x;
            acc[r][1] += xv * wv.y;
            acc[r][2] += xv * wv.z;
            acc[r][3] += xv * wv.w;
        }
    }

    const int c = cq >> 3;          // 32-col chunk index
    const int qin = cq & 7;         // quad within chunk
#pragma unroll
    for (int r = 0; r < RPT; ++r) {
        int gr = row0 + tr * RPT + r;
        if (gr < n) {
            float dd = dis[gr];
            ushort4 pk;
            pk.x = f2h(acc[r][0] * dd);
            pk.y = f2h(acc[r][1] * dd);
            pk.z = f2h(acc[r][2] * dd);
            pk.w = f2h(acc[r][3] * dd);
            // chunk-major: [(c*n + gr)*32 + qin*4] ushorts
            ((ushort4*)Hs)[((size_t)c * n + gr) * 8 + qin] = pk;
        }
    }
}

// ---------------- chunked gather aggregation (+ fused BN stats) ------------
// Per chunk c (32 cols): O[i][32c..32c+32) = dis[i]*(Hs_c[i] + sum Hs_c[src]) + b
// 2 lanes per 64B row; unroll-4 software pipeline over the edge list.
template <int OUTD, bool STATS>
__global__ __launch_bounds__(256) void gather_k(const ushort* __restrict__ Hs,
                                                const float* __restrict__ dis,
                                                const float* __restrict__ b,
                                                const int* __restrict__ row_ptr,
                                                const int* __restrict__ esrc,
                                                float* __restrict__ O,
                                                float* __restrict__ sums,
                                                float* __restrict__ sumsq, int n) {
    constexpr int NCHUNK = OUTD / 32;   // 4 or 2

    __shared__ float s_sum[32];
    __shared__ float s_sq[32];
    if (STATS) {
        if (threadIdx.x < 32) { s_sum[threadIdx.x] = 0.f; s_sq[threadIdx.x] = 0.f; }
        __syncthreads();
    }

    const int chunk = blockIdx.x & (NCHUNK - 1);
    const int nblk  = blockIdx.x / NCHUNK;
    const int g     = threadIdx.x >> 1;     // node within block: 0..127
    const int lane  = threadIdx.x & 1;      // which half of the 64B row
    const int node  = nblk * 128 + g;

    float acc[16];
#pragma unroll
    for (int c = 0; c < 16; ++c) acc[c] = 0.f;
    float o[16];
#pragma unroll
    for (int c = 0; c < 16; ++c) o[c] = 0.f;

    if (node < n) {
        const uint4* Hc = (const uint4*)Hs + (size_t)chunk * n * 4;  // 4 uint4/node

        {   // self row (dis pre-folded into Hs)
            uint4 v0 = Hc[(size_t)node * 4 + lane];
            uint4 v1 = Hc[(size_t)node * 4 + lane + 2];
            ACC8(0, v0);
            ACC8(8, v1);
        }
        const int beg = row_ptr[node];
        const int end = row_ptr[node + 1];
        int j = beg;
        const int end4 = beg + ((end - beg) & ~3);
        for (; j < end4; j += 4) {
            int s0 = esrc[j + 0];
            int s1 = esrc[j + 1];
            int s2 = esrc[j + 2];
            int s3 = esrc[j + 3];
            uint4 a0 = Hc[(size_t)s0 * 4 + lane];
            uint4 a1 = Hc[(size_t)s1 * 4 + lane];
            uint4 a2 = Hc[(size_t)s2 * 4 + lane];
            uint4 a3 = Hc[(size_t)s3 * 4 + lane];
            uint4 c0 = Hc[(size_t)s0 * 4 + lane + 2];
            uint4 c1 = Hc[(size_t)s1 * 4 + lane + 2];
            uint4 c2 = Hc[(size_t)s2 * 4 + lane + 2];
            uint4 c3 = Hc[(size_t)s3 * 4 + lane + 2];
            ACC8(0, a0); ACC8(8, c0);
            ACC8(0, a1); ACC8(8, c1);
            ACC8(0, a2); ACC8(8, c2);
            ACC8(0, a3); ACC8(8, c3);
        }
        for (; j < end; ++j) {
            int s = esrc[j];
            uint4 a = Hc[(size_t)s * 4 + lane];
            uint4 c = Hc[(size_t)s * 4 + lane + 2];
            ACC8(0, a);
            ACC8(8, c);
        }

        float dd = dis[node];
        const float4* B4 = (const float4*)b + chunk * 8 + lane * 2;
        float4 b0 = B4[0];
        float4 b1 = B4[1];
        float4 b2 = B4[4];
        float4 b3 = B4[5];
        o[0]  = acc[0]  * dd + b0.x;
        o[1]  = acc[1]  * dd + b0.y;
        o[2]  = acc[2]  * dd + b0.z;
        o[3]  = acc[3]  * dd + b0.w;
        o[4]  = acc[4]  * dd + b1.x;
        o[5]  = acc[5]  * dd + b1.y;
        o[6]  = acc[6]  * dd + b1.z;
        o[7]  = acc[7]  * dd + b1.w;
        o[8]  = acc[8]  * dd + b2.x;
        o[9]  = acc[9]  * dd + b2.y;
        o[10] = acc[10] * dd + b2.z;
        o[11] = acc[11] * dd + b2.w;
        o[12] = acc[12] * dd + b3.x;
        o[13] = acc[13] * dd + b3.y;
        o[14] = acc[14] * dd + b3.z;
        o[15] = acc[15] * dd + b3.w;

        float4* O4 = (float4*)O + (size_t)node * (OUTD / 4) + chunk * 8 + lane * 2;
        O4[0] = make_float4(o[0], o[1], o[2], o[3]);
        O4[1] = make_float4(o[4], o[5], o[6], o[7]);
        O4[4] = make_float4(o[8], o[9], o[10], o[11]);
        O4[5] = make_float4(o[12], o[13], o[14], o[15]);
    }

    if (STATS) {
        // lanes of equal parity (lane&1) hold the same 16 columns for 32 nodes
        float sv[16], qv[16];
#pragma unroll
        for (int c = 0; c < 16; ++c) { sv[c] = o[c]; qv[c] = o[c] * o[c]; }
#pragma unroll
        for (int c = 0; c < 16; ++c) {
#pragma unroll
            for (int m = 2; m <= 32; m <<= 1) {
                sv[c] += __shfl_xor(sv[c], m);
                qv[c] += __shfl_xor(qv[c], m);
            }
        }
        if ((threadIdx.x & 63) < 2) {
            // lane 0: cols 0-7 and 16-23 of chunk; lane 1: cols 8-15 and 24-31
            int c0 = lane * 8;
            int c1 = 16 + lane * 8;
#pragma unroll
            for (int c = 0; c < 8; ++c) {
                atomicAdd(&s_sum[c0 + c], sv[c]);
                atomicAdd(&s_sq[c0 + c], qv[c]);
                atomicAdd(&s_sum[c1 + c], sv[8 + c]);
                atomicAdd(&s_sq[c1 + c], qv[8 + c]);
            }
        }
        __syncthreads();
        if (threadIdx.x < 32) {
            atomicAdd(&sums[chunk * 32 + threadIdx.x], s_sum[threadIdx.x]);
            atomicAdd(&sumsq[chunk * 32 + threadIdx.x], s_sq[threadIdx.x]);
        }
    }
}

// ---------------- BN finalize: scale/shift from sums ----------------------
__global__ void bn_finalize_k(const float* __restrict__ sums, const float* __restrict__ sumsq,
                              const float* __restrict__ g, const float* __restrict__ be,
                              float* __restrict__ scale, float* __restrict__ shift, int n) {
    int c = threadIdx.x;  // 128 threads
    float inv_n = 1.0f / (float)n;
    float m = sums[c] * inv_n;
    float v = sumsq[c] * inv_n - m * m;
    float sc = rsqrtf(v + 1e-5f) * g[c];
    scale[c] = sc;
    shift[c] = be[c] - m * sc;
}

// ---------------------------------------------------------------------------
extern "C" void kernel_launch(void* const* d_in, const int* in_sizes, int n_in,
                              void* d_out, int out_size, void* d_ws, size_t ws_size,
                              hipStream_t stream) {
    const float* x   = (const float*)d_in[0];
    const int*   ei  = (const int*)d_in[1];
    const float* W1  = (const float*)d_in[2];
    const float* b1  = (const float*)d_in[3];
    const float* g1  = (const float*)d_in[4];
    const float* be1 = (const float*)d_in[5];
    const float* W2  = (const float*)d_in[6];
    const float* b2  = (const float*)d_in[7];
    const float* g2  = (const float*)d_in[8];
    const float* be2 = (const float*)d_in[9];
    const float* W3  = (const float*)d_in[10];
    const float* b3  = (const float*)d_in[11];
    float* out = (float*)d_out;

    const int N = in_sizes[0] / 128;
    const int E = in_sizes[1] / 2;
    const int* src = ei;
    const int* dst = ei + E;

    // ---- workspace layout (persistent) ----
    float* wsp   = (float*)d_ws;
    float* dis   = wsp;                               // N floats
    float* stats = wsp + N;                           // 512 floats
    float* bufA  = stats + 512;                       // N*128 f32 region; Hs (f16) lives here
    float* bufB  = bufA + (size_t)N * 128;            // N*128 f32 (agg out)
    int*   row_ptr = (int*)(bufB + (size_t)N * 128);  // N+1 ints
    int*   esrc    = row_ptr + (N + 1);               // E ints

    ushort* Hs = (ushort*)bufA;                       // [NCHUNK][N][32] f16

    // CSR-build temporaries alias bufA (only used before first GEMM)
    int* deg       = (int*)bufA;          // N ints (later reused as cursor)
    int* blockSums = deg + N;             // ~512 ints
    int* blockOff  = blockSums + 512;     // ~512 ints

    float* sums  = stats;
    float* sumsq = stats + 128;
    float* scale = stats + 256;
    float* shift = stats + 384;

    const int BS = 256;
    dim3 blk(BS);
    const int NB = (N + 255) / 256;

    // ---- CSR build ----
    hipMemsetAsync(deg, 0, (size_t)N * 4, stream);
    deg_count_k<<<dim3((E + BS - 1) / BS), blk, 0, stream>>>(dst, deg, E);
    deg_to_dis_k<<<dim3(NB), blk, 0, stream>>>(deg, dis, N);
    scan_block_reduce_k<<<dim3(NB), blk, 0, stream>>>(deg, blockSums, N);
    scan_top_k<<<dim3(1), dim3(512), 0, stream>>>(blockSums, blockOff, row_ptr, NB, N, E);
    scan_final_k<<<dim3(NB), blk, 0, stream>>>(deg, blockOff, row_ptr, N);
    hipMemsetAsync(deg, 0, (size_t)N * 4, stream);  // deg -> cursor
    edge_scatter_k<<<dim3((E + BS - 1) / BS), blk, 0, stream>>>(src, dst, row_ptr, deg, esrc, E);

    const int gemm_grid = (N + 31) / 32;
    const int NBg = (N + 127) / 128;    // gather node-blocks (128 nodes/block)

    // ---- layer 1 ----
    gemm_k<128, false><<<dim3(gemm_grid), blk, 0, stream>>>(x, W1, nullptr, nullptr, dis, Hs, N);
    hipMemsetAsync(stats, 0, 256 * 4, stream);
    gather_k<128, true><<<dim3(NBg * 4), blk, 0, stream>>>(Hs, dis, b1, row_ptr, esrc,
                                                           bufB, sums, sumsq, N);
    bn_finalize_k<<<dim3(1), dim3(128), 0, stream>>>(sums, sumsq, g1, be1, scale, shift, N);

    // ---- layer 2 (BN applied inside GEMM staging) ----
    gemm_k<128, true><<<dim3(gemm_grid), blk, 0, stream>>>(bufB, W2, scale, shift, dis, Hs, N);
    hipMemsetAsync(stats, 0, 256 * 4, stream);
    gather_k<128, true><<<dim3(NBg * 4), blk, 0, stream>>>(Hs, dis, b2, row_ptr, esrc,
                                                           bufB, sums, sumsq, N);
    bn_finalize_k<<<dim3(1), dim3(128), 0, stream>>>(sums, sumsq, g2, be2, scale, shift, N);

    // ---- layer 3 (OUT = 64, straight to d_out) ----
    gemm_k<64, true><<<dim3(gemm_grid), blk, 0, stream>>>(bufB, W3, scale, shift, dis, Hs, N);
    gather_k<64, false><<<dim3(NBg * 2), blk, 0, stream>>>(Hs, dis, b3, row_ptr, esrc,
                                                           out, nullptr, nullptr, N);
}